// Round 5
// baseline (305.620 us; speedup 1.0000x reference)
//
#include <hip/hip_runtime.h>
#include <stdint.h>

// Problem constants: T=2048, B=4, E=1024, H=16, D=64, M=T*B=8192
// q pre-scale: SCALING * log2(e) so scores are already in log2 domain
#define QSCALE 0.18033688011112042f

typedef unsigned short u16;
typedef unsigned int u32;
typedef __attribute__((ext_vector_type(8))) __bf16 bf16x8;
typedef __attribute__((ext_vector_type(4))) float f32x4;
typedef __attribute__((ext_vector_type(16))) float f32x16;
typedef __attribute__((ext_vector_type(8))) u16 u16x8;
typedef __attribute__((ext_vector_type(4))) u32 u32x4;

__device__ __forceinline__ void gl_lds16(const void* g, void* l) {
  __builtin_amdgcn_global_load_lds(
      (const __attribute__((address_space(1))) void*)g,
      (__attribute__((address_space(3))) void*)l, 16, 0, 0);
}

__device__ __forceinline__ u16 f2bf(float f) {
  unsigned int u = __float_as_uint(f);
  u += 0x7FFFu + ((u >> 16) & 1u);
  return (u16)(u >> 16);
}

// ---------------- f32 -> bf16 convert ----------------
extern "C" __global__ __launch_bounds__(256) void cvt_f32_bf16(
    const float* __restrict__ src, u16* __restrict__ dst, int n) {
  int i = (blockIdx.x * 256 + threadIdx.x) * 4;
  if (i >= n) return;
  float4 v = *(const float4*)(src + i);
  ushort4 o;
  o.x = f2bf(v.x); o.y = f2bf(v.y); o.z = f2bf(v.z); o.w = f2bf(v.w);
  *(ushort4*)(dst + i) = o;
}

// ---------------- QKV projection GEMM ----------------
// q,k scatter to [B,H,T,D]; v scatters directly TRANSPOSED to [B,H,D,T]
// (each 64B line of v^T is covered by one block -> L2 assembles writes).
extern "C" __global__ __launch_bounds__(256) void gemm_qkv(
    const u16* __restrict__ X, const u16* __restrict__ W,
    const float* __restrict__ bias,
    u16* __restrict__ qb, u16* __restrict__ kb, u16* __restrict__ vtb) {
  const int tid = threadIdx.x;
  const int w = tid >> 6, lane = tid & 63;
  const int lg = lane >> 4, ll = lane & 15;
  const int wm = w >> 1, wn = w & 1;
  const int row0A = blockIdx.x * 128;
  const int row0B = blockIdx.y * 128;

  __shared__ __align__(16) u16 As[2][128 * 32];
  __shared__ __align__(16) u16 Bs[2][128 * 32];

  f32x4 acc[4][4] = {};

  const int r_st = tid >> 2;
  const int cb_st = (tid & 3) * 16;

#pragma unroll
  for (int it = 0; it < 2; ++it) {
    gl_lds16((const char*)X + ((size_t)(row0A + it * 64 + r_st) * 1024) * 2 + cb_st,
             (char*)&As[0][0] + it * 4096 + w * 1024);
    gl_lds16((const char*)W + ((size_t)(row0B + it * 64 + r_st) * 1024) * 2 + cb_st,
             (char*)&Bs[0][0] + it * 4096 + w * 1024);
  }

  for (int kt = 0; kt < 32; ++kt) {
    const int cur = kt & 1;
    asm volatile("s_waitcnt vmcnt(0)" ::: "memory");
    __syncthreads();
    if (kt + 1 < 32) {
      const int k0 = (kt + 1) * 32;
#pragma unroll
      for (int it = 0; it < 2; ++it) {
        gl_lds16((const char*)X + ((size_t)(row0A + it * 64 + r_st) * 1024 + k0) * 2 + cb_st,
                 (char*)&As[cur ^ 1][0] + it * 4096 + w * 1024);
        gl_lds16((const char*)W + ((size_t)(row0B + it * 64 + r_st) * 1024 + k0) * 2 + cb_st,
                 (char*)&Bs[cur ^ 1][0] + it * 4096 + w * 1024);
      }
    }
    const u16* Ab = &As[cur][0];
    const u16* Bb = &Bs[cur][0];
    const int kc = lg * 8;
    bf16x8 a[4], bfr[4];
#pragma unroll
    for (int i = 0; i < 4; ++i)
      a[i] = *(const bf16x8*)(Ab + (wm * 64 + i * 16 + ll) * 32 + kc);
#pragma unroll
    for (int j = 0; j < 4; ++j)
      bfr[j] = *(const bf16x8*)(Bb + (wn * 64 + j * 16 + ll) * 32 + kc);
#pragma unroll
    for (int i = 0; i < 4; ++i)
#pragma unroll
      for (int j = 0; j < 4; ++j)
        acc[i][j] = __builtin_amdgcn_mfma_f32_16x16x32_bf16(a[i], bfr[j], acc[i][j], 0, 0, 0);
  }

  const int which = row0B >> 10;
  if (which == 2) {
    // v^T: vt[bh][d][t]
#pragma unroll
    for (int j = 0; j < 4; ++j) {
      const int n = row0B + wn * 64 + j * 16 + ll;
      const float bv = bias[n];
      const int n2 = n & 1023;
      const int hh = n2 >> 6, dd = n2 & 63;
#pragma unroll
      for (int i = 0; i < 4; ++i)
#pragma unroll
        for (int r = 0; r < 4; ++r) {
          const int m = row0A + wm * 64 + i * 16 + lg * 4 + r;
          const int tt = m >> 2, bb = m & 3;
          vtb[(((size_t)(bb * 16 + hh)) * 64 + dd) * 2048 + tt] =
              f2bf(acc[i][j][r] + bv);
        }
    }
  } else {
    u16* dst = which == 0 ? qb : kb;
    const float scl = which == 0 ? QSCALE : 1.0f;
#pragma unroll
    for (int j = 0; j < 4; ++j) {
      const int n = row0B + wn * 64 + j * 16 + ll;
      const float bv = bias[n];
      const int n2 = n & 1023;
      const int hh = n2 >> 6, dd = n2 & 63;
#pragma unroll
      for (int i = 0; i < 4; ++i)
#pragma unroll
        for (int r = 0; r < 4; ++r) {
          const int m = row0A + wm * 64 + i * 16 + lg * 4 + r;
          const int tt = m >> 2, bb = m & 3;
          dst[((size_t)(bb * 16 + hh) * 2048 + tt) * 64 + dd] =
              f2bf((acc[i][j][r] + bv) * scl);
        }
    }
  }
}

// ---------------- flash attention fwd (v4) ----------------
// 32x32 MFMA, P in registers (permlane32_swap), 3-buffer 2-ahead prefetch
// with counted vmcnt + raw s_barrier (T3/T4), mask staged in LDS, XCD swizzle.
extern "C" __global__ __launch_bounds__(256, 3) void flash_fwd(
    const u16* __restrict__ q, const u16* __restrict__ k,
    const u16* __restrict__ vt, const unsigned char* __restrict__ mask,
    u16* __restrict__ attn_pre, float* __restrict__ stat_il) {
  // XCD-chunked swizzle: XCD x gets bh in [x*8, x*8+8) (K/V working set 4MB = L2)
  const int lb = ((blockIdx.x & 7) << 7) + (blockIdx.x >> 3);
  const int bh = lb >> 4, tt = lb & 15;
  const int b = bh >> 4, hd = bh & 15;
  const int t0 = tt * 128;
  const int tid = threadIdx.x, w = tid >> 6, lane = tid & 63;
  const int hl = lane >> 5;  // lane half (0/1)
  const int l31 = lane & 31;

  __shared__ __align__(16) u16 Ks[3][64 * 64];
  __shared__ __align__(16) u16 Vs[3][64 * 64];
  __shared__ __align__(16) unsigned char Ms[2048];

  // Q in registers: row = t0 + w*32 + l31, d = kg*16 + hl*8 + e
  const int qrow = t0 + w * 32 + l31;
  const u16* qp = q + ((size_t)bh * 2048 + qrow) * 64 + hl * 8;
  bf16x8 qreg[4];
#pragma unroll
  for (int kg = 0; kg < 4; ++kg) qreg[kg] = *(const bf16x8*)(qp + kg * 16);

  f32x16 po[2] = {};
  float lsum = 0.f;

  const int slot_r = tid >> 3;
  const int slot_c8 = (tid & 7) ^ (slot_r & 7);

#define STAGE3(buf, s0_)                                                       \
  do {                                                                         \
    _Pragma("unroll") for (int it2 = 0; it2 < 2; ++it2) {                      \
      const int rr = it2 * 32 + slot_r;                                        \
      gl_lds16((const char*)k +                                                \
                   (((size_t)bh * 2048 + (s0_) + rr) * 64 + slot_c8 * 8) * 2,  \
               (char*)&Ks[buf][0] + it2 * 4096 + w * 1024);                    \
      gl_lds16((const char*)vt +                                               \
                   (((size_t)bh * 64 + rr) * 2048 + (s0_) + slot_c8 * 8) * 2,  \
               (char*)&Vs[buf][0] + it2 * 4096 + w * 1024);                    \
    }                                                                          \
  } while (0)

  // prologue: mask first (oldest vmem op), then 2 tiles ahead
  if (w < 2)
    gl_lds16((const char*)mask + b * 2048 + w * 1024 + lane * 16,
             (char*)Ms + w * 1024);
  STAGE3(0, 0);
  STAGE3(1, 64);

  for (int t = 0; t < 32; ++t) {
    // wait: own stage(t) complete (stage(t+1) stays in flight)
    if (t < 31) {
      asm volatile("s_waitcnt vmcnt(4)" ::: "memory");
    } else {
      asm volatile("s_waitcnt vmcnt(0)" ::: "memory");
    }
    __builtin_amdgcn_s_barrier();
    if (t + 2 < 32) STAGE3((t + 2) % 3, (t + 2) * 64);

    const int s0 = t * 64;
    const int cur = t % 3;
    const char* Kb = (const char*)&Ks[cur][0];
    const char* Vb = (const char*)&Vs[cur][0];

    // mask from LDS (lgkm-tracked; keeps vmcnt counting pure)
    u32 mq[8];
#pragma unroll
    for (int kt = 0; kt < 2; ++kt)
#pragma unroll
      for (int j = 0; j < 4; ++j)
        mq[kt * 4 + j] =
            *(const u32*)(Ms + s0 + kt * 32 + j * 8 + hl * 4);
    const u32 anym = mq[0] | mq[1] | mq[2] | mq[3] | mq[4] | mq[5] | mq[6] | mq[7];

#pragma unroll
    for (int kt = 0; kt < 2; ++kt) {
      // QK^T swapped: z[r] = S^T[key][qrow], key = kt*32+(r&3)+8*(r>>2)+4*hl
      f32x16 z = {};
      const int key = kt * 32 + l31;
#pragma unroll
      for (int kg = 0; kg < 4; ++kg) {
        const bf16x8 kf = *(const bf16x8*)(
            Kb + key * 128 + ((((kg << 1) | hl) ^ (key & 7)) << 4));
        z = __builtin_amdgcn_mfma_f32_32x32x16_bf16(kf, qreg[kg], z, 0, 0, 0);
      }

      float ps[16];
#pragma unroll
      for (int r = 0; r < 16; ++r) ps[r] = __builtin_amdgcn_exp2f(z[r]);
      if (__any(anym != 0)) {
#pragma unroll
        for (int r = 0; r < 16; ++r)
          if ((mq[kt * 4 + (r >> 2)] >> ((r & 3) * 8)) & 0xFFu) ps[r] = 0.f;
      }
#pragma unroll
      for (int r = 0; r < 16; ++r) lsum += ps[r];

      // pack to bf16 pairs with single-instr cvt_pk (T12)
      u32 w8[8];
#pragma unroll
      for (int j = 0; j < 4; ++j) {
        asm("v_cvt_pk_bf16_f32 %0, %1, %2"
            : "=v"(w8[2 * j]) : "v"(ps[4 * j]), "v"(ps[4 * j + 1]));
        asm("v_cvt_pk_bf16_f32 %0, %1, %2"
            : "=v"(w8[2 * j + 1]) : "v"(ps[4 * j + 2]), "v"(ps[4 * j + 3]));
      }

      // P -> PV A-operand via permlane32_swap; PV: po += P * V^T
#pragma unroll
      for (int f = 0; f < 2; ++f) {
        u32 d0 = w8[4 * f], d1 = w8[4 * f + 1];
        u32 s0w = w8[4 * f + 2], s1w = w8[4 * f + 3];
        asm volatile("v_permlane32_swap_b32 %0, %1" : "+v"(d0), "+v"(s0w));
        asm volatile("v_permlane32_swap_b32 %0, %1" : "+v"(d1), "+v"(s1w));
        const bf16x8 pa = __builtin_bit_cast(bf16x8, (u32x4){d0, d1, s0w, s1w});
        const int g = kt * 2 + f;
#pragma unroll
        for (int dt = 0; dt < 2; ++dt) {
          const int d = dt * 32 + l31;
          const bf16x8 vf = *(const bf16x8*)(
              Vb + d * 128 + ((((g << 1) | hl) ^ (d & 7)) << 4));
          po[dt] = __builtin_amdgcn_mfma_f32_32x32x16_bf16(pa, vf, po[dt], 0, 0, 0);
        }
      }
    }
  }

  // lanes l and l^32 hold complementary key-halves of row l31
  lsum += __shfl_xor(lsum, 32, 64);
  const float linv = 1.0f / lsum;
  if (lane < 32)
    stat_il[(size_t)bh * 2048 + t0 + w * 32 + lane] = linv;

#pragma unroll
  for (int r = 0; r < 16; ++r) {
    const int qi = (r & 3) + 8 * (r >> 2) + 4 * hl;
    const float lv = __shfl(linv, qi, 64);
    const int trow = t0 + w * 32 + qi;
#pragma unroll
    for (int dt = 0; dt < 2; ++dt) {
      const int dd = dt * 32 + l31;
      attn_pre[((size_t)(trow * 4 + b)) * 1024 + hd * 64 + dd] =
          f2bf(po[dt][r] * lv);
    }
  }
#undef STAGE3
}

// ---------------- attn_w_avg (32x32, lane owns one t-column) ----------
extern "C" __global__ __launch_bounds__(256, 3) void wavg(
    const u16* __restrict__ q, const u16* __restrict__ k,
    const unsigned char* __restrict__ mask,
    const float* __restrict__ stat_il, float* __restrict__ wout) {
  // XCD-chunked swizzle: XCD x gets a contiguous 256-block range (b-locality)
  const int lb = ((blockIdx.x & 7) << 8) + (blockIdx.x >> 3);
  const int b = lb >> 9, tt = (lb >> 5) & 15, st = lb & 31;
  const int t0 = tt * 128, s0 = st * 64;
  const int tid = threadIdx.x, w = tid >> 6, lane = tid & 63;
  const int hl = lane >> 5;
  const int l31 = lane & 31;

  __shared__ __align__(16) u16 Qs[2][128 * 64];  // 32 KB (reused for transpose)
  __shared__ __align__(16) u16 Ks2[2][64 * 64];  // 16 KB

  const int slot_r8 = tid >> 3;
  const int slot_c8 = (tid & 7) ^ (slot_r8 & 7);

  // mask u32s for this s-tile (fixed for whole block)
  u32 mq[8];
#pragma unroll
  for (int kt = 0; kt < 2; ++kt)
#pragma unroll
    for (int j = 0; j < 4; ++j)
      mq[kt * 4 + j] = *(const u32*)(mask + b * 2048 + s0 + kt * 32 + j * 8 + hl * 4);
  const u32 anym = mq[0] | mq[1] | mq[2] | mq[3] | mq[4] | mq[5] | mq[6] | mq[7];
  const bool domask = __any(anym != 0);

#define STAGE_W(buf, hh)                                                       \
  do {                                                                         \
    const size_t qo_ = (size_t)(b * 16 + (hh)) * 2048;                         \
    _Pragma("unroll") for (int i2 = 0; i2 < 4; ++i2) {                         \
      const int rr = i2 * 32 + slot_r8;                                        \
      gl_lds16((const char*)q + ((qo_ + t0 + rr) * 64 + slot_c8 * 8) * 2,      \
               (char*)&Qs[buf][0] + i2 * 4096 + w * 1024);                     \
    }                                                                          \
    _Pragma("unroll") for (int i2 = 0; i2 < 2; ++i2) {                         \
      const int rr = i2 * 32 + slot_r8;                                        \
      gl_lds16((const char*)k + ((qo_ + s0 + rr) * 64 + slot_c8 * 8) * 2,      \
               (char*)&Ks2[buf][0] + i2 * 4096 + w * 1024);                    \
    }                                                                          \
  } while (0)

  STAGE_W(0, 0);
  asm volatile("s_waitcnt vmcnt(0)" ::: "memory");
  __syncthreads();

  float accw[32] = {};
  for (int h = 0; h < 16; ++h) {
    const int cur = h & 1;
    const float ilh =
        stat_il[(size_t)(b * 16 + h) * 2048 + t0 + w * 32 + l31];

    if (h + 1 < 16) STAGE_W(cur ^ 1, h + 1);

    const char* Qb = (const char*)&Qs[cur][0];
    const char* Kb = (const char*)&Ks2[cur][0];

    const int qr = w * 32 + l31;
    bf16x8 qf[4];
#pragma unroll
    for (int kg = 0; kg < 4; ++kg)
      qf[kg] = *(const bf16x8*)(
          Qb + qr * 128 + ((((kg << 1) | hl) ^ (qr & 7)) << 4));

#pragma unroll
    for (int kt = 0; kt < 2; ++kt) {
      f32x16 z = {};
      const int key = kt * 32 + l31;
#pragma unroll
      for (int kg = 0; kg < 4; ++kg) {
        const bf16x8 kf = *(const bf16x8*)(
            Kb + key * 128 + ((((kg << 1) | hl) ^ (key & 7)) << 4));
        z = __builtin_amdgcn_mfma_f32_32x32x16_bf16(kf, qf[kg], z, 0, 0, 0);
      }
      float ps[16];
#pragma unroll
      for (int r = 0; r < 16; ++r) ps[r] = __builtin_amdgcn_exp2f(z[r]);
      if (domask) {
#pragma unroll
        for (int r = 0; r < 16; ++r)
          if ((mq[kt * 4 + (r >> 2)] >> ((r & 3) * 8)) & 0xFFu) ps[r] = 0.f;
      }
#pragma unroll
      for (int r = 0; r < 16; ++r)
        accw[kt * 16 + r] = fmaf(ps[r], ilh, accw[kt * 16 + r]);
    }

    asm volatile("s_waitcnt vmcnt(0)" ::: "memory");
    __syncthreads();
  }

  // transpose via LDS (8 KB per wave in Qs) then coalesced f32x4 writes
  float* tb = ((float*)&Qs[0][0]) + w * 2048;
#pragma unroll
  for (int kt = 0; kt < 2; ++kt)
#pragma unroll
    for (int j = 0; j < 4; ++j) {
      f32x4 qd;
#pragma unroll
      for (int e = 0; e < 4; ++e) qd[e] = accw[kt * 16 + 4 * j + e] * 0.0625f;
      const int slot = kt * 8 + 2 * j + hl;  // 16B slot within 256B row
      *(f32x4*)(tb + l31 * 64 + ((slot ^ (l31 & 7)) << 2)) = qd;
    }
  __syncthreads();
#pragma unroll
  for (int j2 = 0; j2 < 8; ++j2) {
    const int row = j2 * 4 + (lane >> 4);
    const int slot = lane & 15;
    const f32x4 v = *(const f32x4*)(tb + row * 64 + ((slot ^ (row & 7)) << 2));
    *(f32x4*)(wout + ((size_t)b * 2048 + t0 + w * 32 + row) * 2048 + s0 +
              slot * 4) = v;
  }
#undef STAGE_W
}

// ---------------- output projection GEMM ----------------
extern "C" __global__ __launch_bounds__(256) void gemm_out(
    const u16* __restrict__ A, const u16* __restrict__ W,
    const float* __restrict__ bias, float* __restrict__ out) {
  const int tid = threadIdx.x;
  const int w = tid >> 6, lane = tid & 63;
  const int lg = lane >> 4, ll = lane & 15;
  const int wm = w >> 1, wn = w & 1;
  const int row0A = blockIdx.x * 128;
  const int row0B = blockIdx.y * 128;

  __shared__ __align__(16) u16 As[2][128 * 32];
  __shared__ __align__(16) u16 Bs[2][128 * 32];

  f32x4 acc[4][4] = {};
  const int r_st = tid >> 2;
  const int cb_st = (tid & 3) * 16;

#pragma unroll
  for (int it = 0; it < 2; ++it) {
    gl_lds16((const char*)A + ((size_t)(row0A + it * 64 + r_st) * 1024) * 2 + cb_st,
             (char*)&As[0][0] + it * 4096 + w * 1024);
    gl_lds16((const char*)W + ((size_t)(row0B + it * 64 + r_st) * 1024) * 2 + cb_st,
             (char*)&Bs[0][0] + it * 4096 + w * 1024);
  }

  for (int kt = 0; kt < 32; ++kt) {
    const int cur = kt & 1;
    asm volatile("s_waitcnt vmcnt(0)" ::: "memory");
    __syncthreads();
    if (kt + 1 < 32) {
      const int k0 = (kt + 1) * 32;
#pragma unroll
      for (int it = 0; it < 2; ++it) {
        gl_lds16((const char*)A + ((size_t)(row0A + it * 64 + r_st) * 1024 + k0) * 2 + cb_st,
                 (char*)&As[cur ^ 1][0] + it * 4096 + w * 1024);
        gl_lds16((const char*)W + ((size_t)(row0B + it * 64 + r_st) * 1024 + k0) * 2 + cb_st,
                 (char*)&Bs[cur ^ 1][0] + it * 4096 + w * 1024);
      }
    }
    const u16* Ab = &As[cur][0];
    const u16* Bb = &Bs[cur][0];
    const int kc = lg * 8;
    bf16x8 a[4], bfr[4];
#pragma unroll
    for (int i = 0; i < 4; ++i)
      a[i] = *(const bf16x8*)(Ab + (wm * 64 + i * 16 + ll) * 32 + kc);
#pragma unroll
    for (int j = 0; j < 4; ++j)
      bfr[j] = *(const bf16x8*)(Bb + (wn * 64 + j * 16 + ll) * 32 + kc);
#pragma unroll
    for (int i = 0; i < 4; ++i)
#pragma unroll
      for (int j = 0; j < 4; ++j)
        acc[i][j] = __builtin_amdgcn_mfma_f32_16x16x32_bf16(a[i], bfr[j], acc[i][j], 0, 0, 0);
  }

#pragma unroll
  for (int j = 0; j < 4; ++j) {
    const int n = row0B + wn * 64 + j * 16 + ll;
    const float bv = bias[n];
#pragma unroll
    for (int i = 0; i < 4; ++i)
#pragma unroll
      for (int r = 0; r < 4; ++r) {
        const int m = row0A + wm * 64 + i * 16 + lg * 4 + r;
        out[(size_t)m * 1024 + n] = acc[i][j][r] + bv;
      }
  }
}

extern "C" void kernel_launch(void* const* d_in, const int* in_sizes, int n_in,
                              void* d_out, int out_size, void* d_ws, size_t ws_size,
                              hipStream_t stream) {
  const float* query = (const float*)d_in[0];
  const unsigned char* mask = (const unsigned char*)d_in[1];
  const float* w_in = (const float*)d_in[2];
  const float* b_in = (const float*)d_in[3];
  const float* w_out = (const float*)d_in[4];
  const float* b_out = (const float*)d_in[5];

  float* out0 = (float*)d_out;                   // attn [T,B,E] = 8388608 f32
  float* outw = out0 + (size_t)8388608;          // attn_w_avg [B,T,S]

  char* ws = (char*)d_ws;
  u16* Xbf   = (u16*)(ws + 0);            // 16 MB  query bf16 [8192][1024]
  u16* Wqkv  = (u16*)(ws + 16777216);     // 6 MB   in_proj_weight bf16
  u16* Woutb = (u16*)(ws + 23068672);     // 2 MB   out_w bf16
  u16* qb    = (u16*)(ws + 25165824);     // 16 MB  q [B,H,T,D] bf16 (scaled)
  u16* kb    = (u16*)(ws + 41943040);     // 16 MB  k [B,H,T,D]
  u16* vtb   = (u16*)(ws + 75497472);     // 16 MB  v^T [B,H,D,T]
  u16* ap    = (u16*)(ws + 92274688);     // 16 MB  attn_pre bf16 [8192][1024]
  float* sil = (float*)(ws + 109051904);  // 0.5 MB row 1/l [B*H][T]

  cvt_f32_bf16<<<8192, 256, 0, stream>>>(query, Xbf, 8388608);
  cvt_f32_bf16<<<3072, 256, 0, stream>>>(w_in, Wqkv, 3145728);
  cvt_f32_bf16<<<1024, 256, 0, stream>>>(w_out, Woutb, 1048576);
  gemm_qkv<<<dim3(64, 24), 256, 0, stream>>>(Xbf, Wqkv, b_in, qb, kb, vtb);
  flash_fwd<<<1024, 256, 0, stream>>>(qb, kb, vtb, mask, ap, sil);
  wavg<<<2048, 256, 0, stream>>>(qb, kb, mask, sil, outw);
  gemm_out<<<dim3(64, 8), 256, 0, stream>>>(ap, Woutb, b_out, out0);
}

// Round 6
// 282.927 us; speedup vs baseline: 1.0802x; 1.0802x over previous
//
#include <hip/hip_runtime.h>
#include <stdint.h>

// Problem constants: T=2048, B=4, E=1024, H=16, D=64, M=T*B=8192
// q pre-scale: SCALING * log2(e) so scores are already in log2 domain
#define QSCALE 0.18033688011112042f

typedef unsigned short u16;
typedef unsigned int u32;
typedef __attribute__((ext_vector_type(8))) __bf16 bf16x8;
typedef __attribute__((ext_vector_type(4))) float f32x4;
typedef __attribute__((ext_vector_type(16))) float f32x16;
typedef __attribute__((ext_vector_type(8))) u16 u16x8;
typedef __attribute__((ext_vector_type(4))) u32 u32x4;

__device__ __forceinline__ void gl_lds16(const void* g, void* l) {
  __builtin_amdgcn_global_load_lds(
      (const __attribute__((address_space(1))) void*)g,
      (__attribute__((address_space(3))) void*)l, 16, 0, 0);
}

__device__ __forceinline__ u16 f2bf(float f) {
  unsigned int u = __float_as_uint(f);
  u += 0x7FFFu + ((u >> 16) & 1u);
  return (u16)(u >> 16);
}

// ---------------- f32 -> bf16 convert (all three inputs, one launch) -------
// dst regions are contiguous in ws: [query 8388608][w_in 3145728][w_out 1048576]
extern "C" __global__ __launch_bounds__(256) void cvt_all(
    const float* __restrict__ query, const float* __restrict__ w_in,
    const float* __restrict__ w_out, u16* __restrict__ dst) {
  int i = (blockIdx.x * 256 + threadIdx.x) * 4;
  const float* src;
  int off;
  if (i < 8388608) {
    src = query; off = i;
  } else if (i < 11534336) {
    src = w_in; off = i - 8388608;
  } else {
    src = w_out; off = i - 11534336;
  }
  float4 v = *(const float4*)(src + off);
  ushort4 o;
  o.x = f2bf(v.x); o.y = f2bf(v.y); o.z = f2bf(v.z); o.w = f2bf(v.w);
  *(ushort4*)(dst + i) = o;
}

// ---------------- QKV projection GEMM ----------------
// C[m,n] = sum_k X[m,k] * W[n,k] + bias[n];  m = t*4+b
// epilogue scatters into q/k/v [B,H,T,D] bf16 (q scaled by SCALING*log2e)
extern "C" __global__ __launch_bounds__(256) void gemm_qkv(
    const u16* __restrict__ X, const u16* __restrict__ W,
    const float* __restrict__ bias,
    u16* __restrict__ qb, u16* __restrict__ kb, u16* __restrict__ vb) {
  const int tid = threadIdx.x;
  const int w = tid >> 6, lane = tid & 63;
  const int lg = lane >> 4, ll = lane & 15;
  const int wm = w >> 1, wn = w & 1;
  const int row0A = blockIdx.x * 128;
  const int row0B = blockIdx.y * 128;

  __shared__ __align__(16) u16 As[2][128 * 32];
  __shared__ __align__(16) u16 Bs[2][128 * 32];

  f32x4 acc[4][4] = {};

  const int r_st = tid >> 2;
  const int cb_st = (tid & 3) * 16;

#pragma unroll
  for (int it = 0; it < 2; ++it) {
    gl_lds16((const char*)X + ((size_t)(row0A + it * 64 + r_st) * 1024) * 2 + cb_st,
             (char*)&As[0][0] + it * 4096 + w * 1024);
    gl_lds16((const char*)W + ((size_t)(row0B + it * 64 + r_st) * 1024) * 2 + cb_st,
             (char*)&Bs[0][0] + it * 4096 + w * 1024);
  }

  for (int kt = 0; kt < 32; ++kt) {
    const int cur = kt & 1;
    asm volatile("s_waitcnt vmcnt(0)" ::: "memory");
    __syncthreads();
    if (kt + 1 < 32) {
      const int k0 = (kt + 1) * 32;
#pragma unroll
      for (int it = 0; it < 2; ++it) {
        gl_lds16((const char*)X + ((size_t)(row0A + it * 64 + r_st) * 1024 + k0) * 2 + cb_st,
                 (char*)&As[cur ^ 1][0] + it * 4096 + w * 1024);
        gl_lds16((const char*)W + ((size_t)(row0B + it * 64 + r_st) * 1024 + k0) * 2 + cb_st,
                 (char*)&Bs[cur ^ 1][0] + it * 4096 + w * 1024);
      }
    }
    const u16* Ab = &As[cur][0];
    const u16* Bb = &Bs[cur][0];
    const int kc = lg * 8;
    bf16x8 a[4], bfr[4];
#pragma unroll
    for (int i = 0; i < 4; ++i)
      a[i] = *(const bf16x8*)(Ab + (wm * 64 + i * 16 + ll) * 32 + kc);
#pragma unroll
    for (int j = 0; j < 4; ++j)
      bfr[j] = *(const bf16x8*)(Bb + (wn * 64 + j * 16 + ll) * 32 + kc);
#pragma unroll
    for (int i = 0; i < 4; ++i)
#pragma unroll
      for (int j = 0; j < 4; ++j)
        acc[i][j] = __builtin_amdgcn_mfma_f32_16x16x32_bf16(a[i], bfr[j], acc[i][j], 0, 0, 0);
  }

  const int which = row0B >> 10;
  u16* dst = which == 0 ? qb : (which == 1 ? kb : vb);
  const float scl = which == 0 ? QSCALE : 1.0f;
#pragma unroll
  for (int j = 0; j < 4; ++j) {
    const int n = row0B + wn * 64 + j * 16 + ll;
    const float bv = bias[n];
    const int n2 = n & 1023;
    const int hh = n2 >> 6, dd = n2 & 63;
#pragma unroll
    for (int i = 0; i < 4; ++i)
#pragma unroll
      for (int r = 0; r < 4; ++r) {
        const int m = row0A + wm * 64 + i * 16 + lg * 4 + r;
        const int tt = m >> 2, bb = m & 3;
        dst[((size_t)(bb * 16 + hh) * 2048 + tt) * 64 + dd] = f2bf((acc[i][j][r] + bv) * scl);
      }
  }
}

// ---------------- V transpose: [BH][T][D] -> [BH][D][T] ----------------
extern "C" __global__ __launch_bounds__(256) void transpose_v(
    const u16* __restrict__ v, u16* __restrict__ vt) {
  const int blk = blockIdx.x;
  const int bh = blk >> 5, tt = blk & 31;
  const int t0 = tt * 64;
  const int tid = threadIdx.x;
  __shared__ __align__(16) u16 tile[64][72];
  const u16* src = v + ((size_t)bh * 2048 + t0) * 64;
#pragma unroll
  for (int it = 0; it < 2; ++it) {
    const int r = it * 32 + (tid >> 3);
    const int c = (tid & 7) * 8;
    *(u16x8*)(&tile[r][c]) = *(const u16x8*)(src + (size_t)r * 64 + c);
  }
  __syncthreads();
  u16* dstb = vt + (size_t)bh * 64 * 2048 + t0;
#pragma unroll
  for (int it = 0; it < 2; ++it) {
    const int d = it * 32 + (tid >> 3);
    const int s = (tid & 7) * 8;
    u16x8 o;
#pragma unroll
    for (int jj = 0; jj < 8; ++jj) o[jj] = tile[s + jj][d];
    *(u16x8*)(dstb + (size_t)d * 2048 + s) = o;
  }
}

// ---------------- flash attention fwd (v4) ----------------
// 32x32 MFMA, P in registers (permlane32_swap), 3-buffer 2-ahead prefetch
// with counted vmcnt + raw s_barrier (T3/T4), mask staged in LDS, XCD swizzle.
extern "C" __global__ __launch_bounds__(256, 3) void flash_fwd(
    const u16* __restrict__ q, const u16* __restrict__ k,
    const u16* __restrict__ vt, const unsigned char* __restrict__ mask,
    u16* __restrict__ attn_pre, float* __restrict__ stat_il) {
  // XCD-chunked swizzle: XCD x gets bh in [x*8, x*8+8) (K/V working set 4MB = L2)
  const int lb = ((blockIdx.x & 7) << 7) + (blockIdx.x >> 3);
  const int bh = lb >> 4, tt = lb & 15;
  const int b = bh >> 4, hd = bh & 15;
  const int t0 = tt * 128;
  const int tid = threadIdx.x, w = tid >> 6, lane = tid & 63;
  const int hl = lane >> 5;  // lane half (0/1)
  const int l31 = lane & 31;

  __shared__ __align__(16) u16 Ks[3][64 * 64];
  __shared__ __align__(16) u16 Vs[3][64 * 64];
  __shared__ __align__(16) unsigned char Ms[2048];

  // Q in registers: row = t0 + w*32 + l31, d = kg*16 + hl*8 + e
  const int qrow = t0 + w * 32 + l31;
  const u16* qp = q + ((size_t)bh * 2048 + qrow) * 64 + hl * 8;
  bf16x8 qreg[4];
#pragma unroll
  for (int kg = 0; kg < 4; ++kg) qreg[kg] = *(const bf16x8*)(qp + kg * 16);

  f32x16 po[2] = {};
  float lsum = 0.f;

  const int slot_r = tid >> 3;
  const int slot_c8 = (tid & 7) ^ (slot_r & 7);

#define STAGE3(buf, s0_)                                                       \
  do {                                                                         \
    _Pragma("unroll") for (int it2 = 0; it2 < 2; ++it2) {                      \
      const int rr = it2 * 32 + slot_r;                                        \
      gl_lds16((const char*)k +                                                \
                   (((size_t)bh * 2048 + (s0_) + rr) * 64 + slot_c8 * 8) * 2,  \
               (char*)&Ks[buf][0] + it2 * 4096 + w * 1024);                    \
      gl_lds16((const char*)vt +                                               \
                   (((size_t)bh * 64 + rr) * 2048 + (s0_) + slot_c8 * 8) * 2,  \
               (char*)&Vs[buf][0] + it2 * 4096 + w * 1024);                    \
    }                                                                          \
  } while (0)

  // prologue: mask first (oldest vmem op), then 2 tiles ahead
  if (w < 2)
    gl_lds16((const char*)mask + b * 2048 + w * 1024 + lane * 16,
             (char*)Ms + w * 1024);
  STAGE3(0, 0);
  STAGE3(1, 64);

  for (int t = 0; t < 32; ++t) {
    // wait: own stage(t) complete (stage(t+1) stays in flight)
    if (t < 31) {
      asm volatile("s_waitcnt vmcnt(4)" ::: "memory");
    } else {
      asm volatile("s_waitcnt vmcnt(0)" ::: "memory");
    }
    __builtin_amdgcn_s_barrier();
    if (t + 2 < 32) STAGE3((t + 2) % 3, (t + 2) * 64);

    const int s0 = t * 64;
    const int cur = t % 3;
    const char* Kb = (const char*)&Ks[cur][0];
    const char* Vb = (const char*)&Vs[cur][0];

    // mask from LDS (lgkm-tracked; keeps vmcnt counting pure)
    u32 mq[8];
#pragma unroll
    for (int kt = 0; kt < 2; ++kt)
#pragma unroll
      for (int j = 0; j < 4; ++j)
        mq[kt * 4 + j] =
            *(const u32*)(Ms + s0 + kt * 32 + j * 8 + hl * 4);
    const u32 anym = mq[0] | mq[1] | mq[2] | mq[3] | mq[4] | mq[5] | mq[6] | mq[7];

#pragma unroll
    for (int kt = 0; kt < 2; ++kt) {
      // QK^T swapped: z[r] = S^T[key][qrow], key = kt*32+(r&3)+8*(r>>2)+4*hl
      f32x16 z = {};
      const int key = kt * 32 + l31;
#pragma unroll
      for (int kg = 0; kg < 4; ++kg) {
        const bf16x8 kf = *(const bf16x8*)(
            Kb + key * 128 + ((((kg << 1) | hl) ^ (key & 7)) << 4));
        z = __builtin_amdgcn_mfma_f32_32x32x16_bf16(kf, qreg[kg], z, 0, 0, 0);
      }

      float ps[16];
#pragma unroll
      for (int r = 0; r < 16; ++r) ps[r] = __builtin_amdgcn_exp2f(z[r]);
      if (__any(anym != 0)) {
#pragma unroll
        for (int r = 0; r < 16; ++r)
          if ((mq[kt * 4 + (r >> 2)] >> ((r & 3) * 8)) & 0xFFu) ps[r] = 0.f;
      }
#pragma unroll
      for (int r = 0; r < 16; ++r) lsum += ps[r];

      // pack to bf16 pairs with single-instr cvt_pk (T12)
      u32 w8[8];
#pragma unroll
      for (int j = 0; j < 4; ++j) {
        asm("v_cvt_pk_bf16_f32 %0, %1, %2"
            : "=v"(w8[2 * j]) : "v"(ps[4 * j]), "v"(ps[4 * j + 1]));
        asm("v_cvt_pk_bf16_f32 %0, %1, %2"
            : "=v"(w8[2 * j + 1]) : "v"(ps[4 * j + 2]), "v"(ps[4 * j + 3]));
      }

      // P -> PV A-operand via permlane32_swap; PV: po += P * V^T
#pragma unroll
      for (int f = 0; f < 2; ++f) {
        u32 d0 = w8[4 * f], d1 = w8[4 * f + 1];
        u32 s0w = w8[4 * f + 2], s1w = w8[4 * f + 3];
        asm volatile("v_permlane32_swap_b32 %0, %1" : "+v"(d0), "+v"(s0w));
        asm volatile("v_permlane32_swap_b32 %0, %1" : "+v"(d1), "+v"(s1w));
        const bf16x8 pa = __builtin_bit_cast(bf16x8, (u32x4){d0, d1, s0w, s1w});
        const int g = kt * 2 + f;
#pragma unroll
        for (int dt = 0; dt < 2; ++dt) {
          const int d = dt * 32 + l31;
          const bf16x8 vf = *(const bf16x8*)(
              Vb + d * 128 + ((((g << 1) | hl) ^ (d & 7)) << 4));
          po[dt] = __builtin_amdgcn_mfma_f32_32x32x16_bf16(pa, vf, po[dt], 0, 0, 0);
        }
      }
    }
  }

  // lanes l and l^32 hold complementary key-halves of row l31
  lsum += __shfl_xor(lsum, 32, 64);
  const float linv = 1.0f / lsum;
  if (lane < 32)
    stat_il[(size_t)bh * 2048 + t0 + w * 32 + lane] = linv;

#pragma unroll
  for (int r = 0; r < 16; ++r) {
    const int qi = (r & 3) + 8 * (r >> 2) + 4 * hl;
    const float lv = __shfl(linv, qi, 64);
    const int trow = t0 + w * 32 + qi;
#pragma unroll
    for (int dt = 0; dt < 2; ++dt) {
      const int dd = dt * 32 + l31;
      attn_pre[((size_t)(trow * 4 + b)) * 1024 + hd * 64 + dd] =
          f2bf(po[dt][r] * lv);
    }
  }
#undef STAGE3
}

// ---------------- attn_w_avg (32x32, lane owns one t-column) ----------
extern "C" __global__ __launch_bounds__(256, 3) void wavg(
    const u16* __restrict__ q, const u16* __restrict__ k,
    const unsigned char* __restrict__ mask,
    const float* __restrict__ stat_il, float* __restrict__ wout) {
  // XCD-chunked swizzle: XCD x gets a contiguous 256-block range (b-locality)
  const int lb = ((blockIdx.x & 7) << 8) + (blockIdx.x >> 3);
  const int b = lb >> 9, tt = (lb >> 5) & 15, st = lb & 31;
  const int t0 = tt * 128, s0 = st * 64;
  const int tid = threadIdx.x, w = tid >> 6, lane = tid & 63;
  const int hl = lane >> 5;
  const int l31 = lane & 31;

  __shared__ __align__(16) u16 Qs[2][128 * 64];  // 32 KB (reused for transpose)
  __shared__ __align__(16) u16 Ks2[2][64 * 64];  // 16 KB

  const int slot_r8 = tid >> 3;
  const int slot_c8 = (tid & 7) ^ (slot_r8 & 7);

  // mask u32s for this s-tile (fixed for whole block)
  u32 mq[8];
#pragma unroll
  for (int kt = 0; kt < 2; ++kt)
#pragma unroll
    for (int j = 0; j < 4; ++j)
      mq[kt * 4 + j] = *(const u32*)(mask + b * 2048 + s0 + kt * 32 + j * 8 + hl * 4);
  const u32 anym = mq[0] | mq[1] | mq[2] | mq[3] | mq[4] | mq[5] | mq[6] | mq[7];
  const bool domask = __any(anym != 0);

#define STAGE_W(buf, hh)                                                       \
  do {                                                                         \
    const size_t qo_ = (size_t)(b * 16 + (hh)) * 2048;                         \
    _Pragma("unroll") for (int i2 = 0; i2 < 4; ++i2) {                         \
      const int rr = i2 * 32 + slot_r8;                                        \
      gl_lds16((const char*)q + ((qo_ + t0 + rr) * 64 + slot_c8 * 8) * 2,      \
               (char*)&Qs[buf][0] + i2 * 4096 + w * 1024);                     \
    }                                                                          \
    _Pragma("unroll") for (int i2 = 0; i2 < 2; ++i2) {                         \
      const int rr = i2 * 32 + slot_r8;                                        \
      gl_lds16((const char*)k + ((qo_ + s0 + rr) * 64 + slot_c8 * 8) * 2,      \
               (char*)&Ks2[buf][0] + i2 * 4096 + w * 1024);                    \
    }                                                                          \
  } while (0)

  STAGE_W(0, 0);
  asm volatile("s_waitcnt vmcnt(0)" ::: "memory");
  __syncthreads();

  float accw[32] = {};
  for (int h = 0; h < 16; ++h) {
    const int cur = h & 1;
    const float ilh =
        stat_il[(size_t)(b * 16 + h) * 2048 + t0 + w * 32 + l31];

    if (h + 1 < 16) STAGE_W(cur ^ 1, h + 1);

    const char* Qb = (const char*)&Qs[cur][0];
    const char* Kb = (const char*)&Ks2[cur][0];

    const int qr = w * 32 + l31;
    bf16x8 qf[4];
#pragma unroll
    for (int kg = 0; kg < 4; ++kg)
      qf[kg] = *(const bf16x8*)(
          Qb + qr * 128 + ((((kg << 1) | hl) ^ (qr & 7)) << 4));

#pragma unroll
    for (int kt = 0; kt < 2; ++kt) {
      f32x16 z = {};
      const int key = kt * 32 + l31;
#pragma unroll
      for (int kg = 0; kg < 4; ++kg) {
        const bf16x8 kf = *(const bf16x8*)(
            Kb + key * 128 + ((((kg << 1) | hl) ^ (key & 7)) << 4));
        z = __builtin_amdgcn_mfma_f32_32x32x16_bf16(kf, qf[kg], z, 0, 0, 0);
      }
      float ps[16];
#pragma unroll
      for (int r = 0; r < 16; ++r) ps[r] = __builtin_amdgcn_exp2f(z[r]);
      if (domask) {
#pragma unroll
        for (int r = 0; r < 16; ++r)
          if ((mq[kt * 4 + (r >> 2)] >> ((r & 3) * 8)) & 0xFFu) ps[r] = 0.f;
      }
#pragma unroll
      for (int r = 0; r < 16; ++r)
        accw[kt * 16 + r] = fmaf(ps[r], ilh, accw[kt * 16 + r]);
    }

    asm volatile("s_waitcnt vmcnt(0)" ::: "memory");
    __syncthreads();
  }

  // transpose via LDS (8 KB per wave in Qs) then coalesced f32x4 writes
  float* tb = ((float*)&Qs[0][0]) + w * 2048;
#pragma unroll
  for (int kt = 0; kt < 2; ++kt)
#pragma unroll
    for (int j = 0; j < 4; ++j) {
      f32x4 qd;
#pragma unroll
      for (int e = 0; e < 4; ++e) qd[e] = accw[kt * 16 + 4 * j + e] * 0.0625f;
      const int slot = kt * 8 + 2 * j + hl;  // 16B slot within 256B row
      *(f32x4*)(tb + l31 * 64 + ((slot ^ (l31 & 7)) << 2)) = qd;
    }
  __syncthreads();
#pragma unroll
  for (int j2 = 0; j2 < 8; ++j2) {
    const int row = j2 * 4 + (lane >> 4);
    const int slot = lane & 15;
    const f32x4 v = *(const f32x4*)(tb + row * 64 + ((slot ^ (row & 7)) << 2));
    *(f32x4*)(wout + ((size_t)b * 2048 + t0 + w * 32 + row) * 2048 + s0 +
              slot * 4) = v;
  }
#undef STAGE_W
}

// ---------------- output projection GEMM ----------------
extern "C" __global__ __launch_bounds__(256) void gemm_out(
    const u16* __restrict__ A, const u16* __restrict__ W,
    const float* __restrict__ bias, float* __restrict__ out) {
  const int tid = threadIdx.x;
  const int w = tid >> 6, lane = tid & 63;
  const int lg = lane >> 4, ll = lane & 15;
  const int wm = w >> 1, wn = w & 1;
  const int row0A = blockIdx.x * 128;
  const int row0B = blockIdx.y * 128;

  __shared__ __align__(16) u16 As[2][128 * 32];
  __shared__ __align__(16) u16 Bs[2][128 * 32];

  f32x4 acc[4][4] = {};
  const int r_st = tid >> 2;
  const int cb_st = (tid & 3) * 16;

#pragma unroll
  for (int it = 0; it < 2; ++it) {
    gl_lds16((const char*)A + ((size_t)(row0A + it * 64 + r_st) * 1024) * 2 + cb_st,
             (char*)&As[0][0] + it * 4096 + w * 1024);
    gl_lds16((const char*)W + ((size_t)(row0B + it * 64 + r_st) * 1024) * 2 + cb_st,
             (char*)&Bs[0][0] + it * 4096 + w * 1024);
  }

  for (int kt = 0; kt < 32; ++kt) {
    const int cur = kt & 1;
    asm volatile("s_waitcnt vmcnt(0)" ::: "memory");
    __syncthreads();
    if (kt + 1 < 32) {
      const int k0 = (kt + 1) * 32;
#pragma unroll
      for (int it = 0; it < 2; ++it) {
        gl_lds16((const char*)A + ((size_t)(row0A + it * 64 + r_st) * 1024 + k0) * 2 + cb_st,
                 (char*)&As[cur ^ 1][0] + it * 4096 + w * 1024);
        gl_lds16((const char*)W + ((size_t)(row0B + it * 64 + r_st) * 1024 + k0) * 2 + cb_st,
                 (char*)&Bs[cur ^ 1][0] + it * 4096 + w * 1024);
      }
    }
    const u16* Ab = &As[cur][0];
    const u16* Bb = &Bs[cur][0];
    const int kc = lg * 8;
    bf16x8 a[4], bfr[4];
#pragma unroll
    for (int i = 0; i < 4; ++i)
      a[i] = *(const bf16x8*)(Ab + (wm * 64 + i * 16 + ll) * 32 + kc);
#pragma unroll
    for (int j = 0; j < 4; ++j)
      bfr[j] = *(const bf16x8*)(Bb + (wn * 64 + j * 16 + ll) * 32 + kc);
#pragma unroll
    for (int i = 0; i < 4; ++i)
#pragma unroll
      for (int j = 0; j < 4; ++j)
        acc[i][j] = __builtin_amdgcn_mfma_f32_16x16x32_bf16(a[i], bfr[j], acc[i][j], 0, 0, 0);
  }

#pragma unroll
  for (int j = 0; j < 4; ++j) {
    const int n = row0B + wn * 64 + j * 16 + ll;
    const float bv = bias[n];
#pragma unroll
    for (int i = 0; i < 4; ++i)
#pragma unroll
      for (int r = 0; r < 4; ++r) {
        const int m = row0A + wm * 64 + i * 16 + lg * 4 + r;
        out[(size_t)m * 1024 + n] = acc[i][j][r] + bv;
      }
  }
}

extern "C" void kernel_launch(void* const* d_in, const int* in_sizes, int n_in,
                              void* d_out, int out_size, void* d_ws, size_t ws_size,
                              hipStream_t stream) {
  const float* query = (const float*)d_in[0];
  const unsigned char* mask = (const unsigned char*)d_in[1];
  const float* w_in = (const float*)d_in[2];
  const float* b_in = (const float*)d_in[3];
  const float* w_out = (const float*)d_in[4];
  const float* b_out = (const float*)d_in[5];

  float* out0 = (float*)d_out;                   // attn [T,B,E] = 8388608 f32
  float* outw = out0 + (size_t)8388608;          // attn_w_avg [B,T,S]

  char* ws = (char*)d_ws;
  u16* Xbf   = (u16*)(ws + 0);            // 16 MB  query bf16 [8192][1024]
  u16* Wqkv  = (u16*)(ws + 16777216);     // 6 MB   in_proj_weight bf16
  u16* Woutb = (u16*)(ws + 23068672);     // 2 MB   out_w bf16
  u16* qb    = (u16*)(ws + 25165824);     // 16 MB  q [B,H,T,D] bf16 (scaled)
  u16* kb    = (u16*)(ws + 41943040);     // 16 MB  k [B,H,T,D]
  u16* vb    = (u16*)(ws + 58720256);     // 16 MB  v [B,H,T,D]
  u16* vtb   = (u16*)(ws + 75497472);     // 16 MB  v^T [B,H,D,T]
  u16* ap    = (u16*)(ws + 92274688);     // 16 MB  attn_pre bf16 [8192][1024]
  float* sil = (float*)(ws + 109051904);  // 0.5 MB row 1/l [B*H][T]

  cvt_all<<<12288, 256, 0, stream>>>(query, w_in, w_out, Xbf);
  gemm_qkv<<<dim3(64, 24), 256, 0, stream>>>(Xbf, Wqkv, b_in, qb, kb, vb);
  transpose_v<<<2048, 256, 0, stream>>>(vb, vtb);
  flash_fwd<<<1024, 256, 0, stream>>>(qb, kb, vtb, mask, ap, sil);
  wavg<<<2048, 256, 0, stream>>>(qb, kb, mask, sil, outw);
  gemm_out<<<dim3(64, 8), 256, 0, stream>>>(ap, Woutb, b_out, out0);
}